// Round 5
// baseline (125.615 us; speedup 1.0000x reference)
//
#include <hip/hip_runtime.h>
#include <hip/hip_bf16.h>

// Problem constants (from reference)
#define F        256
#define NNODES   100000
#define NROOTS   8192
#define SAMP     10
#define KDIM     512        // 2*F concat width
#define HOP1ROWS (NROOTS * SAMP)   // 81920

typedef __bf16   bf16x8  __attribute__((ext_vector_type(8)));
typedef unsigned short ushort8 __attribute__((ext_vector_type(8)));
typedef unsigned int   uint4v  __attribute__((ext_vector_type(4)));
typedef float    f32x4   __attribute__((ext_vector_type(4)));

__device__ __forceinline__ unsigned short f2bf(float f) {
    unsigned int u = __builtin_bit_cast(unsigned int, f);
    u += 0x7FFFu + ((u >> 16) & 1u);      // round-to-nearest-even
    return (unsigned short)(u >> 16);
}

// ---------------------------------------------------------------------------
// prep_kernel: fused weight conversion + feature-matrix bf16 conversion.
// Blocks [0,128): W1/W2 f32 -> bf16 B-fragment order
//   frag[((cb*16 + kblk)*64 + lane)*8 + e] = W[k][col]
//   col = cb*16 + (lane&15),  k = kblk*32 + (lane>>4)*8 + e
// Blocks [128, 128+2048): FM f32 [100000][256] -> FMb bf16 (grid-stride)
// ---------------------------------------------------------------------------
__global__ __launch_bounds__(256)
void prep_kernel(const float* __restrict__ FM,
                 const float* __restrict__ W1, const float* __restrict__ W2,
                 unsigned short* __restrict__ FMb,
                 unsigned short* __restrict__ W1f, unsigned short* __restrict__ W2f)
{
    if (blockIdx.x < 128) {
        const int id   = blockIdx.x * 256 + threadIdx.x;   // 32768 total
        const int lane = id & 63;
        const int grp  = id >> 6;          // 512 groups
        const int kblk = grp & 15;
        const int cb   = (grp >> 4) & 15;
        const int mat  = grp >> 8;         // 0 -> W1, 1 -> W2
        const float* W = mat ? W2 : W1;
        unsigned short* dst = mat ? W2f : W1f;

        const int col   = cb * 16 + (lane & 15);
        const int kbase = kblk * 32 + (lane >> 4) * 8;
        ushort8 v;
#pragma unroll
        for (int e = 0; e < 8; ++e) v[e] = f2bf(W[(kbase + e) * 256 + col]);
        *(ushort8*)&dst[(((cb * 16 + kblk) * 64) + lane) * 8] = v;
    } else {
        const int bid2   = blockIdx.x - 128;
        const int stride = (gridDim.x - 128) * 256;
        const int total  = NNODES * F / 8;             // 3,200,000 groups of 8
        for (int i = bid2 * 256 + threadIdx.x; i < total; i += stride) {
            const float4* p = (const float4*)(FM + (size_t)i * 8);
            float4 x = p[0], y = p[1];
            ushort8 v;
            v[0]=f2bf(x.x); v[1]=f2bf(x.y); v[2]=f2bf(x.z); v[3]=f2bf(x.w);
            v[4]=f2bf(y.x); v[5]=f2bf(y.y); v[6]=f2bf(y.z); v[7]=f2bf(y.w);
            *(ushort8*)&FMb[(size_t)i * 8] = v;
        }
    }
}

// ---------------------------------------------------------------------------
// Standalone wconv (fallback path only)
// ---------------------------------------------------------------------------
__global__ __launch_bounds__(256)
void wconv_kernel(const float* __restrict__ W1, const float* __restrict__ W2,
                  unsigned short* __restrict__ W1f, unsigned short* __restrict__ W2f)
{
    const int id   = blockIdx.x * 256 + threadIdx.x;   // 32768 total
    const int lane = id & 63;
    const int grp  = id >> 6;
    const int kblk = grp & 15;
    const int cb   = (grp >> 4) & 15;
    const int mat  = grp >> 8;
    const float* W = mat ? W2 : W1;
    unsigned short* dst = mat ? W2f : W1f;

    const int col   = cb * 16 + (lane & 15);
    const int kbase = kblk * 32 + (lane >> 4) * 8;
    ushort8 v;
#pragma unroll
    for (int e = 0; e < 8; ++e) v[e] = f2bf(W[(kbase + e) * 256 + col]);
    *(ushort8*)&dst[(((cb * 16 + kblk) * 64) + lane) * 8] = v;
}

// ---------------------------------------------------------------------------
// Fused gather + mean + layer-1 GEMM (+ optional group-of-10 mean reduce).
// GT = unsigned short (bf16 table) or float (fallback).
// NT = threads per block (256/512/1024). LDS (80KB at TM=80) caps residency
// at 2 blocks/CU, so NT=1024 -> 32 waves/CU (100% occupancy) for gather MLP.
// __launch_bounds__ min-waves NT/128 forces VGPR<=64 at NT=1024.
// ---------------------------------------------------------------------------
template <int TM, bool REDUCE, typename GT, int NT>
__global__ __launch_bounds__(NT, NT / 128)
void hop_kernel(const GT* __restrict__ FMg,
                const int* __restrict__ selfIdx,
                const int* __restrict__ nbIdx,
                const unsigned short* __restrict__ Wfrag,
                unsigned short* __restrict__ outComb)
{
    __shared__ __align__(16) unsigned short A_lds[TM * KDIM];   // bf16 tile, swizzled
    const int t   = threadIdx.x;
    const int bid = blockIdx.x;

    // ---- Phase A: gather self + mean(10 neighbors) into LDS bf16 ----------
    // NT/32 rows in flight; strided row loop with guard (TM need not divide).
    {
        const int c0 = (t & 31) * 8;      // 8 elements per thread per row
#pragma unroll 1
        for (int r = (t >> 5); r < TM; r += NT / 32) {
            const int rg = bid * TM + r;
            const int self = selfIdx[rg];
            if constexpr (sizeof(GT) == 2) {
                ushort8 sv = *(const ushort8*)(FMg + (size_t)self * F + c0);
                *(ushort8*)&A_lds[(r * KDIM + c0) ^ ((r & 7) << 3)] = sv;

                float a0=0,a1=0,a2=0,a3=0,a4=0,a5=0,a6=0,a7=0;
#pragma unroll
                for (int k = 0; k < SAMP; ++k) {
                    const int idx = nbIdx[rg * SAMP + k];
                    uint4v u = __builtin_bit_cast(uint4v,
                        *(const ushort8*)(FMg + (size_t)idx * F + c0));
                    a0 += __builtin_bit_cast(float, u[0] << 16);
                    a1 += __builtin_bit_cast(float, u[0] & 0xFFFF0000u);
                    a2 += __builtin_bit_cast(float, u[1] << 16);
                    a3 += __builtin_bit_cast(float, u[1] & 0xFFFF0000u);
                    a4 += __builtin_bit_cast(float, u[2] << 16);
                    a5 += __builtin_bit_cast(float, u[2] & 0xFFFF0000u);
                    a6 += __builtin_bit_cast(float, u[3] << 16);
                    a7 += __builtin_bit_cast(float, u[3] & 0xFFFF0000u);
                }
                ushort8 m;
                m[0]=f2bf(a0*0.1f); m[1]=f2bf(a1*0.1f); m[2]=f2bf(a2*0.1f); m[3]=f2bf(a3*0.1f);
                m[4]=f2bf(a4*0.1f); m[5]=f2bf(a5*0.1f); m[6]=f2bf(a6*0.1f); m[7]=f2bf(a7*0.1f);
                *(ushort8*)&A_lds[(r * KDIM + F + c0) ^ ((r & 7) << 3)] = m;
            } else {
                const float4* sp = (const float4*)(FMg + (size_t)self * F + c0);
                float4 s0 = sp[0], s1 = sp[1];
                ushort8 v;
                v[0]=f2bf(s0.x); v[1]=f2bf(s0.y); v[2]=f2bf(s0.z); v[3]=f2bf(s0.w);
                v[4]=f2bf(s1.x); v[5]=f2bf(s1.y); v[6]=f2bf(s1.z); v[7]=f2bf(s1.w);
                *(ushort8*)&A_lds[(r * KDIM + c0) ^ ((r & 7) << 3)] = v;

                float a0=0,a1=0,a2=0,a3=0,a4=0,a5=0,a6=0,a7=0;
#pragma unroll
                for (int k = 0; k < SAMP; ++k) {
                    const int idx = nbIdx[rg * SAMP + k];
                    const float4* np_ = (const float4*)(FMg + (size_t)idx * F + c0);
                    float4 n0 = np_[0], n1 = np_[1];
                    a0+=n0.x; a1+=n0.y; a2+=n0.z; a3+=n0.w;
                    a4+=n1.x; a5+=n1.y; a6+=n1.z; a7+=n1.w;
                }
                ushort8 m;
                m[0]=f2bf(a0*0.1f); m[1]=f2bf(a1*0.1f); m[2]=f2bf(a2*0.1f); m[3]=f2bf(a3*0.1f);
                m[4]=f2bf(a4*0.1f); m[5]=f2bf(a5*0.1f); m[6]=f2bf(a6*0.1f); m[7]=f2bf(a7*0.1f);
                *(ushort8*)&A_lds[(r * KDIM + F + c0) ^ ((r & 7) << 3)] = m;
            }
        }
    }
    __syncthreads();

    // ---- Phase B: MFMA GEMM [TM,512] x [512,256] --------------------------
    constexpr int RM  = TM / 16;
    constexpr int CPW = 1024 / NT;    // col-blocks of 16 per wave (4/2/1)
    const int wv   = t >> 6;
    const int lane = t & 63;
    const int l16  = lane & 15;
    const int koff = (lane >> 4) * 8;

    f32x4 acc[RM][CPW];
#pragma unroll
    for (int i = 0; i < RM; ++i)
#pragma unroll
        for (int j = 0; j < CPW; ++j) acc[i][j] = (f32x4){0.f, 0.f, 0.f, 0.f};

#pragma unroll 4
    for (int kb = 0; kb < 16; ++kb) {
        const int kbase = kb * 32 + koff;
        ushort8 af[RM];
#pragma unroll
        for (int i = 0; i < RM; ++i) {
            const int row = i * 16 + l16;
            af[i] = *(const ushort8*)&A_lds[(row * KDIM + kbase) ^ ((row & 7) << 3)];
        }
#pragma unroll
        for (int j = 0; j < CPW; ++j) {
            const int cb = wv * CPW + j;
            ushort8 bf = *(const ushort8*)&Wfrag[(((cb * 16 + kb) * 64) + lane) * 8];
#pragma unroll
            for (int i = 0; i < RM; ++i) {
                acc[i][j] = __builtin_amdgcn_mfma_f32_16x16x32_bf16(
                    __builtin_bit_cast(bf16x8, af[i]),
                    __builtin_bit_cast(bf16x8, bf),
                    acc[i][j], 0, 0, 0);
            }
        }
    }

    // ---- Phase C: epilogue ------------------------------------------------
    if (REDUCE) {
        __syncthreads();                       // all waves done reading A_lds
        float* C_lds = (float*)A_lds;          // reuse as f32 [TM][256]
#pragma unroll
        for (int i = 0; i < RM; ++i)
#pragma unroll
            for (int j = 0; j < CPW; ++j) {
                const int col = (wv * CPW + j) * 16 + l16;
#pragma unroll
                for (int rg_ = 0; rg_ < 4; ++rg_) {
                    const int row = i * 16 + (lane >> 4) * 4 + rg_;
                    C_lds[row * 256 + col] = fmaxf(acc[i][j][rg_], 0.f);
                }
            }
        __syncthreads();
        constexpr int GH = NT / 256;            // column-halves of threads
        constexpr int GPT = (TM / 10) / GH;     // root groups per thread
        const int c  = t & 255;
        const int gh = t >> 8;
#pragma unroll
        for (int g2 = 0; g2 < GPT; ++g2) {
            const int g = gh * GPT + g2;
            float s = 0.f;
#pragma unroll
            for (int j = 0; j < SAMP; ++j) s += C_lds[(g * SAMP + j) * 256 + c];
            outComb[((size_t)(bid * (TM / 10) + g)) * KDIM + F + c] = f2bf(s * 0.1f);
        }
    } else {
#pragma unroll
        for (int i = 0; i < RM; ++i)
#pragma unroll
            for (int j = 0; j < CPW; ++j) {
                const int col = (wv * CPW + j) * 16 + l16;
#pragma unroll
                for (int rg_ = 0; rg_ < 4; ++rg_) {
                    const int row = bid * TM + i * 16 + (lane >> 4) * 4 + rg_;
                    outComb[(size_t)row * KDIM + col] = f2bf(fmaxf(acc[i][j][rg_], 0.f));
                }
            }
    }
}

// ---------------------------------------------------------------------------
// root_kernel: fused hop32 + layer-2 GEMM.
//   Phase A : gather self(forest0) + mean(forest1 nbrs) -> A_lds bf16 [32][512]
//   Phase B1: H1 = relu(A @ W1)          (MFMA, acc in regs)
//   Phase C1: H1 -> bf16 -> A_lds[:,0:256]; stage comb[:,256:512] (hop80 out)
//             into A_lds[:,256:512]
//   Phase B2: out = relu(A2 @ W2) -> f32 global
// Numerically identical to hop32(write comb lo) + gemm2(read comb).
// ---------------------------------------------------------------------------
__global__ __launch_bounds__(256)
void root_kernel(const unsigned short* __restrict__ FMb,
                 const int* __restrict__ forest0,
                 const int* __restrict__ forest1,
                 const unsigned short* __restrict__ W1f,
                 const unsigned short* __restrict__ W2f,
                 const unsigned short* __restrict__ comb,   // hop80 half lives here
                 float* __restrict__ out)
{
    constexpr int TM = 32;
    __shared__ __align__(16) unsigned short A_lds[TM * KDIM];
    const int t   = threadIdx.x;
    const int bid = blockIdx.x;

    // ---- Phase A: gather (identical to hop_kernel NT=256 bf16 path) ------
    {
        const int rsub = t >> 5;
        const int c0   = (t & 31) * 8;
#pragma unroll 1
        for (int rr = 0; rr < TM; rr += 8) {
            const int r  = rr + rsub;
            const int rg = bid * TM + r;
            const int self = forest0[rg];
            ushort8 sv = *(const ushort8*)(FMb + (size_t)self * F + c0);
            *(ushort8*)&A_lds[(r * KDIM + c0) ^ ((r & 7) << 3)] = sv;

            float a0=0,a1=0,a2=0,a3=0,a4=0,a5=0,a6=0,a7=0;
#pragma unroll
            for (int k = 0; k < SAMP; ++k) {
                const int idx = forest1[rg * SAMP + k];
                uint4v u = __builtin_bit_cast(uint4v,
                    *(const ushort8*)(FMb + (size_t)idx * F + c0));
                a0 += __builtin_bit_cast(float, u[0] << 16);
                a1 += __builtin_bit_cast(float, u[0] & 0xFFFF0000u);
                a2 += __builtin_bit_cast(float, u[1] << 16);
                a3 += __builtin_bit_cast(float, u[1] & 0xFFFF0000u);
                a4 += __builtin_bit_cast(float, u[2] << 16);
                a5 += __builtin_bit_cast(float, u[2] & 0xFFFF0000u);
                a6 += __builtin_bit_cast(float, u[3] << 16);
                a7 += __builtin_bit_cast(float, u[3] & 0xFFFF0000u);
            }
            ushort8 m;
            m[0]=f2bf(a0*0.1f); m[1]=f2bf(a1*0.1f); m[2]=f2bf(a2*0.1f); m[3]=f2bf(a3*0.1f);
            m[4]=f2bf(a4*0.1f); m[5]=f2bf(a5*0.1f); m[6]=f2bf(a6*0.1f); m[7]=f2bf(a7*0.1f);
            *(ushort8*)&A_lds[(r * KDIM + F + c0) ^ ((r & 7) << 3)] = m;
        }
    }
    __syncthreads();

    constexpr int RM = TM / 16;   // 2
    const int wv = t >> 6, lane = t & 63, l16 = lane & 15, koff = (lane >> 4) * 8;

    f32x4 acc[RM][4];
#pragma unroll
    for (int i = 0; i < RM; ++i)
#pragma unroll
        for (int j = 0; j < 4; ++j) acc[i][j] = (f32x4){0.f, 0.f, 0.f, 0.f};

    // ---- Phase B1: layer-1 GEMM ------------------------------------------
#pragma unroll 4
    for (int kb = 0; kb < 16; ++kb) {
        const int kbase = kb * 32 + koff;
        ushort8 af[RM];
#pragma unroll
        for (int i = 0; i < RM; ++i) {
            const int row = i * 16 + l16;
            af[i] = *(const ushort8*)&A_lds[(row * KDIM + kbase) ^ ((row & 7) << 3)];
        }
#pragma unroll
        for (int j = 0; j < 4; ++j) {
            const int cb = wv * 4 + j;
            ushort8 bf = *(const ushort8*)&W1f[(((cb * 16 + kb) * 64) + lane) * 8];
#pragma unroll
            for (int i = 0; i < RM; ++i) {
                acc[i][j] = __builtin_amdgcn_mfma_f32_16x16x32_bf16(
                    __builtin_bit_cast(bf16x8, af[i]),
                    __builtin_bit_cast(bf16x8, bf),
                    acc[i][j], 0, 0, 0);
            }
        }
    }

    // ---- Phase C1: H1 -> LDS lo half; stage hop80 half -> LDS hi half -----
    __syncthreads();                           // all B1 reads of A_lds done
#pragma unroll
    for (int i = 0; i < RM; ++i)
#pragma unroll
        for (int j = 0; j < 4; ++j) {
            const int col = (wv * 4 + j) * 16 + l16;
#pragma unroll
            for (int rg_ = 0; rg_ < 4; ++rg_) {
                const int row = i * 16 + (lane >> 4) * 4 + rg_;
                A_lds[(row * KDIM + col) ^ ((row & 7) << 3)] =
                    f2bf(fmaxf(acc[i][j][rg_], 0.f));
            }
        }
    for (int i = t; i < TM * 256 / 8; i += 256) {     // 4 ushort8 per thread
        const int row = i >> 5;
        const int c8  = (i & 31) * 8;
        ushort8 v = *(const ushort8*)&comb[((size_t)(bid * TM + row)) * KDIM + 256 + c8];
        *(ushort8*)&A_lds[(row * KDIM + 256 + c8) ^ ((row & 7) << 3)] = v;
    }
    __syncthreads();

    // ---- Phase B2: layer-2 GEMM ------------------------------------------
#pragma unroll
    for (int i = 0; i < RM; ++i)
#pragma unroll
        for (int j = 0; j < 4; ++j) acc[i][j] = (f32x4){0.f, 0.f, 0.f, 0.f};

#pragma unroll 4
    for (int kb = 0; kb < 16; ++kb) {
        const int kbase = kb * 32 + koff;
        ushort8 af[RM];
#pragma unroll
        for (int i = 0; i < RM; ++i) {
            const int row = i * 16 + l16;
            af[i] = *(const ushort8*)&A_lds[(row * KDIM + kbase) ^ ((row & 7) << 3)];
        }
#pragma unroll
        for (int j = 0; j < 4; ++j) {
            const int cb = wv * 4 + j;
            ushort8 bf = *(const ushort8*)&W2f[(((cb * 16 + kb) * 64) + lane) * 8];
#pragma unroll
            for (int i = 0; i < RM; ++i) {
                acc[i][j] = __builtin_amdgcn_mfma_f32_16x16x32_bf16(
                    __builtin_bit_cast(bf16x8, af[i]),
                    __builtin_bit_cast(bf16x8, bf),
                    acc[i][j], 0, 0, 0);
            }
        }
    }

#pragma unroll
    for (int i = 0; i < RM; ++i)
#pragma unroll
        for (int j = 0; j < 4; ++j) {
            const int col = (wv * 4 + j) * 16 + l16;
#pragma unroll
            for (int rg_ = 0; rg_ < 4; ++rg_) {
                const int row = bid * TM + i * 16 + (lane >> 4) * 4 + rg_;
                out[(size_t)row * 256 + col] = fmaxf(acc[i][j][rg_], 0.f);
            }
        }
}

// ---------------------------------------------------------------------------
// Layer-2 GEMM (fallback path only)
// ---------------------------------------------------------------------------
__global__ __launch_bounds__(256)
void gemm2_kernel(const unsigned short* __restrict__ comb,
                  const unsigned short* __restrict__ Wfrag,
                  float* __restrict__ out)
{
    constexpr int TM = 32;
    __shared__ __align__(16) unsigned short B_lds[TM * KDIM];
    const int t   = threadIdx.x;
    const int bid = blockIdx.x;

    for (int i = t; i < TM * KDIM / 8; i += 256) {
        const int row = i >> 6;
        const int c8  = (i & 63) * 8;
        ushort8 v = *(const ushort8*)&comb[((size_t)(bid * TM + row)) * KDIM + c8];
        *(ushort8*)&B_lds[(row * KDIM + c8) ^ ((row & 7) << 3)] = v;
    }
    __syncthreads();

    constexpr int RM = TM / 16;   // 2
    const int wv = t >> 6, lane = t & 63, l16 = lane & 15, koff = (lane >> 4) * 8;
    f32x4 acc[RM][4];
#pragma unroll
    for (int i = 0; i < RM; ++i)
#pragma unroll
        for (int j = 0; j < 4; ++j) acc[i][j] = (f32x4){0.f, 0.f, 0.f, 0.f};

#pragma unroll 4
    for (int kb = 0; kb < 16; ++kb) {
        const int kbase = kb * 32 + koff;
        ushort8 af[RM];
#pragma unroll
        for (int i = 0; i < RM; ++i) {
            const int row = i * 16 + l16;
            af[i] = *(const ushort8*)&B_lds[(row * KDIM + kbase) ^ ((row & 7) << 3)];
        }
#pragma unroll
        for (int j = 0; j < 4; ++j) {
            const int cb = wv * 4 + j;
            ushort8 bf = *(const ushort8*)&Wfrag[(((cb * 16 + kb) * 64) + lane) * 8];
#pragma unroll
            for (int i = 0; i < RM; ++i) {
                acc[i][j] = __builtin_amdgcn_mfma_f32_16x16x32_bf16(
                    __builtin_bit_cast(bf16x8, af[i]),
                    __builtin_bit_cast(bf16x8, bf),
                    acc[i][j], 0, 0, 0);
            }
        }
    }

#pragma unroll
    for (int i = 0; i < RM; ++i)
#pragma unroll
        for (int j = 0; j < 4; ++j) {
            const int col = (wv * 4 + j) * 16 + l16;
#pragma unroll
            for (int rg_ = 0; rg_ < 4; ++rg_) {
                const int row = bid * TM + i * 16 + (lane >> 4) * 4 + rg_;
                out[(size_t)row * 256 + col] = fmaxf(acc[i][j][rg_], 0.f);
            }
        }
}

// ---------------------------------------------------------------------------
extern "C" void kernel_launch(void* const* d_in, const int* in_sizes, int n_in,
                              void* d_out, int out_size, void* d_ws, size_t ws_size,
                              hipStream_t stream)
{
    const int*   forest0 = (const int*)d_in[0];    // [8192]
    const int*   forest1 = (const int*)d_in[1];    // [8192*10]
    const int*   forest2 = (const int*)d_in[2];    // [81920*10]
    const float* FM      = (const float*)d_in[3];  // [100000*256]
    const float* W1      = (const float*)d_in[4];  // [512*256]
    const float* W2      = (const float*)d_in[5];  // [512*256]
    float*       out     = (float*)d_out;          // [8192*256]

    const size_t fmbElems  = (size_t)NNODES * F;                 // 25,600,000
    const size_t wElems    = (size_t)512 * 256;                  // per weight
    const size_t combElems = (size_t)NROOTS * KDIM;              // 4,194,304
    const size_t needBytes = (fmbElems + 2 * wElems + combElems) * sizeof(unsigned short);

    if (ws_size >= needBytes) {
        unsigned short* FMb  = (unsigned short*)d_ws;
        unsigned short* W1f  = FMb + fmbElems;
        unsigned short* W2f  = W1f + wElems;
        unsigned short* comb = W2f + wElems;

        // 1) fused weight + feature conversion
        prep_kernel<<<dim3(128 + 2048), dim3(256), 0, stream>>>(
            FM, W1, W2, FMb, W1f, W2f);
        // 2) hop-1 level: 81920 rows, 80/block, 1024 threads
        //    (2 blocks/CU, 32 waves/CU = 100% occupancy for gather MLP)
        hop_kernel<80, true, unsigned short, 1024>
            <<<dim3(HOP1ROWS / 80), dim3(1024), 0, stream>>>(
            FMb, forest1, forest2, W1f, comb);
        // 3) fused root gather + layer-1 + layer-2 -> out
        root_kernel<<<dim3(NROOTS / 32), dim3(256), 0, stream>>>(
            FMb, forest0, forest1, W1f, W2f, comb, out);
    } else {
        // fallback: original f32-gather path (~8.6 MB workspace)
        unsigned short* W1f  = (unsigned short*)d_ws;
        unsigned short* W2f  = W1f + wElems;
        unsigned short* comb = W2f + wElems;

        wconv_kernel<<<dim3(128), dim3(256), 0, stream>>>(W1, W2, W1f, W2f);
        hop_kernel<80, true, float, 256>
            <<<dim3(HOP1ROWS / 80), dim3(256), 0, stream>>>(
            FM, forest1, forest2, W1f, comb);
        hop_kernel<32, false, float, 256>
            <<<dim3(NROOTS / 32), dim3(256), 0, stream>>>(
            FM, forest0, forest1, W1f, comb);
        gemm2_kernel<<<dim3(NROOTS / 32), dim3(256), 0, stream>>>(comb, W2f, out);
    }
}

// Round 6
// 118.240 us; speedup vs baseline: 1.0624x; 1.0624x over previous
//
#include <hip/hip_runtime.h>
#include <hip/hip_bf16.h>
#include <hip/hip_cooperative_groups.h>

namespace cg = cooperative_groups;

// Problem constants (from reference)
#define F        256
#define NNODES   100000
#define NROOTS   8192
#define SAMP     10
#define KDIM     512        // 2*F concat width
#define HOP1ROWS (NROOTS * SAMP)   // 81920

typedef __bf16   bf16x8  __attribute__((ext_vector_type(8)));
typedef unsigned short ushort8 __attribute__((ext_vector_type(8)));
typedef unsigned int   uint4v  __attribute__((ext_vector_type(4)));
typedef float    f32x4   __attribute__((ext_vector_type(4)));

__device__ __forceinline__ unsigned short f2bf(float f) {
    unsigned int u = __builtin_bit_cast(unsigned int, f);
    u += 0x7FFFu + ((u >> 16) & 1u);      // round-to-nearest-even
    return (unsigned short)(u >> 16);
}

// ===========================================================================
// Cooperative mega-kernel: prep -> grid.sync -> hop80 (2 tiles/block)
// -> grid.sync -> root (fused hop32+layer2).
// 512 blocks x 512 threads, 80KB LDS -> exactly 2 blocks/CU co-resident.
// All phase bodies are byte-identical math to the proven r4 kernels.
// ===========================================================================
__global__ __launch_bounds__(512, 4)
void mega_kernel(const float* __restrict__ FM,
                 const float* __restrict__ W1, const float* __restrict__ W2,
                 const int* __restrict__ forest0,
                 const int* __restrict__ forest1,
                 const int* __restrict__ forest2,
                 unsigned short* __restrict__ FMb,
                 unsigned short* __restrict__ W1f,
                 unsigned short* __restrict__ W2f,
                 unsigned short* __restrict__ comb,
                 float* __restrict__ out)
{
    __shared__ __align__(16) unsigned short A_lds[80 * KDIM];   // 80 KB
    const int t   = threadIdx.x;
    const int bid = blockIdx.x;        // 512 blocks
    cg::grid_group grid = cg::this_grid();

    // ---------------- Phase 0: prep (weights + feature table) -------------
    if (bid < 64) {                    // 64*512 = 32768 ids, same map as wconv
        const int id   = bid * 512 + t;
        const int lane = id & 63;
        const int grp  = id >> 6;
        const int kblk = grp & 15;
        const int cb   = (grp >> 4) & 15;
        const int mat  = grp >> 8;
        const float* W = mat ? W2 : W1;
        unsigned short* dst = mat ? W2f : W1f;
        const int col   = cb * 16 + (lane & 15);
        const int kbase = kblk * 32 + (lane >> 4) * 8;
        ushort8 v;
#pragma unroll
        for (int e = 0; e < 8; ++e) v[e] = f2bf(W[(kbase + e) * 256 + col]);
        *(ushort8*)&dst[(((cb * 16 + kblk) * 64) + lane) * 8] = v;
    }
    {
        const int stride = 512 * 512;
        const int total  = NNODES * F / 8;
        for (int i = bid * 512 + t; i < total; i += stride) {
            const float4* p = (const float4*)(FM + (size_t)i * 8);
            float4 x = p[0], y = p[1];
            ushort8 v;
            v[0]=f2bf(x.x); v[1]=f2bf(x.y); v[2]=f2bf(x.z); v[3]=f2bf(x.w);
            v[4]=f2bf(y.x); v[5]=f2bf(y.y); v[6]=f2bf(y.z); v[7]=f2bf(y.w);
            *(ushort8*)&FMb[(size_t)i * 8] = v;
        }
    }
    grid.sync();

    // ---------------- Phase 1: hop80, tiles bid and bid+512 ---------------
    {
        const int wv   = t >> 6;          // 8 waves
        const int lane = t & 63;
        const int l16  = lane & 15;
        const int koff = (lane >> 4) * 8;
        const int rsub = t >> 5;          // 16 rows in flight
        const int c0   = (t & 31) * 8;

#pragma unroll 1
        for (int tile = bid; tile < HOP1ROWS / 80; tile += 512) {
            // ---- Phase A: gather self + mean(10 nbrs) -> LDS bf16 --------
#pragma unroll 1
            for (int rr = 0; rr < 80; rr += 16) {
                const int r  = rr + rsub;
                const int rg = tile * 80 + r;
                const int self = forest1[rg];
                ushort8 sv = *(const ushort8*)(FMb + (size_t)self * F + c0);
                *(ushort8*)&A_lds[(r * KDIM + c0) ^ ((r & 7) << 3)] = sv;

                float a0=0,a1=0,a2=0,a3=0,a4=0,a5=0,a6=0,a7=0;
#pragma unroll
                for (int k = 0; k < SAMP; ++k) {
                    const int idx = forest2[rg * SAMP + k];
                    uint4v u = __builtin_bit_cast(uint4v,
                        *(const ushort8*)(FMb + (size_t)idx * F + c0));
                    a0 += __builtin_bit_cast(float, u[0] << 16);
                    a1 += __builtin_bit_cast(float, u[0] & 0xFFFF0000u);
                    a2 += __builtin_bit_cast(float, u[1] << 16);
                    a3 += __builtin_bit_cast(float, u[1] & 0xFFFF0000u);
                    a4 += __builtin_bit_cast(float, u[2] << 16);
                    a5 += __builtin_bit_cast(float, u[2] & 0xFFFF0000u);
                    a6 += __builtin_bit_cast(float, u[3] << 16);
                    a7 += __builtin_bit_cast(float, u[3] & 0xFFFF0000u);
                }
                ushort8 m;
                m[0]=f2bf(a0*0.1f); m[1]=f2bf(a1*0.1f); m[2]=f2bf(a2*0.1f); m[3]=f2bf(a3*0.1f);
                m[4]=f2bf(a4*0.1f); m[5]=f2bf(a5*0.1f); m[6]=f2bf(a6*0.1f); m[7]=f2bf(a7*0.1f);
                *(ushort8*)&A_lds[(r * KDIM + F + c0) ^ ((r & 7) << 3)] = m;
            }
            __syncthreads();

            // ---- Phase B: MFMA GEMM [80,512]x[512,256], CPW=2 ------------
            f32x4 acc[5][2];
#pragma unroll
            for (int i = 0; i < 5; ++i)
#pragma unroll
                for (int j = 0; j < 2; ++j) acc[i][j] = (f32x4){0.f,0.f,0.f,0.f};

#pragma unroll 4
            for (int kb = 0; kb < 16; ++kb) {
                const int kbase = kb * 32 + koff;
                ushort8 af[5];
#pragma unroll
                for (int i = 0; i < 5; ++i) {
                    const int row = i * 16 + l16;
                    af[i] = *(const ushort8*)&A_lds[(row * KDIM + kbase) ^ ((row & 7) << 3)];
                }
#pragma unroll
                for (int j = 0; j < 2; ++j) {
                    const int cb = wv * 2 + j;
                    ushort8 bf = *(const ushort8*)&W1f[(((cb * 16 + kb) * 64) + lane) * 8];
#pragma unroll
                    for (int i = 0; i < 5; ++i) {
                        acc[i][j] = __builtin_amdgcn_mfma_f32_16x16x32_bf16(
                            __builtin_bit_cast(bf16x8, af[i]),
                            __builtin_bit_cast(bf16x8, bf),
                            acc[i][j], 0, 0, 0);
                    }
                }
            }

            // ---- Phase C: relu -> C_lds, group-of-10 mean -> comb hi -----
            __syncthreads();
            float* C_lds = (float*)A_lds;
#pragma unroll
            for (int i = 0; i < 5; ++i)
#pragma unroll
                for (int j = 0; j < 2; ++j) {
                    const int col = (wv * 2 + j) * 16 + l16;
#pragma unroll
                    for (int rg_ = 0; rg_ < 4; ++rg_) {
                        const int row = i * 16 + (lane >> 4) * 4 + rg_;
                        C_lds[row * 256 + col] = fmaxf(acc[i][j][rg_], 0.f);
                    }
                }
            __syncthreads();
            {
                const int c  = t & 255;
                const int gh = t >> 8;
#pragma unroll
                for (int g2 = 0; g2 < 4; ++g2) {
                    const int g = gh * 4 + g2;
                    float s = 0.f;
#pragma unroll
                    for (int j = 0; j < SAMP; ++j) s += C_lds[(g * SAMP + j) * 256 + c];
                    comb[((size_t)(tile * 8 + g)) * KDIM + F + c] = f2bf(s * 0.1f);
                }
            }
            __syncthreads();           // protect A_lds reuse by next tile
        }
    }
    grid.sync();

    // ---------------- Phase 2: root (blocks 0..255) -----------------------
    if (bid < 256) {
        const int wv   = t >> 6;
        const int lane = t & 63;
        const int l16  = lane & 15;
        const int koff = (lane >> 4) * 8;

        // ---- Phase A: gather self(forest0) + mean(forest1) ---------------
        {
            const int rsub = t >> 5;
            const int c0   = (t & 31) * 8;
#pragma unroll 1
            for (int rr = 0; rr < 32; rr += 16) {
                const int r  = rr + rsub;
                const int rg = bid * 32 + r;
                const int self = forest0[rg];
                ushort8 sv = *(const ushort8*)(FMb + (size_t)self * F + c0);
                *(ushort8*)&A_lds[(r * KDIM + c0) ^ ((r & 7) << 3)] = sv;

                float a0=0,a1=0,a2=0,a3=0,a4=0,a5=0,a6=0,a7=0;
#pragma unroll
                for (int k = 0; k < SAMP; ++k) {
                    const int idx = forest1[rg * SAMP + k];
                    uint4v u = __builtin_bit_cast(uint4v,
                        *(const ushort8*)(FMb + (size_t)idx * F + c0));
                    a0 += __builtin_bit_cast(float, u[0] << 16);
                    a1 += __builtin_bit_cast(float, u[0] & 0xFFFF0000u);
                    a2 += __builtin_bit_cast(float, u[1] << 16);
                    a3 += __builtin_bit_cast(float, u[1] & 0xFFFF0000u);
                    a4 += __builtin_bit_cast(float, u[2] << 16);
                    a5 += __builtin_bit_cast(float, u[2] & 0xFFFF0000u);
                    a6 += __builtin_bit_cast(float, u[3] << 16);
                    a7 += __builtin_bit_cast(float, u[3] & 0xFFFF0000u);
                }
                ushort8 m;
                m[0]=f2bf(a0*0.1f); m[1]=f2bf(a1*0.1f); m[2]=f2bf(a2*0.1f); m[3]=f2bf(a3*0.1f);
                m[4]=f2bf(a4*0.1f); m[5]=f2bf(a5*0.1f); m[6]=f2bf(a6*0.1f); m[7]=f2bf(a7*0.1f);
                *(ushort8*)&A_lds[(r * KDIM + F + c0) ^ ((r & 7) << 3)] = m;
            }
        }
        __syncthreads();

        f32x4 acc[2][2];
#pragma unroll
        for (int i = 0; i < 2; ++i)
#pragma unroll
            for (int j = 0; j < 2; ++j) acc[i][j] = (f32x4){0.f,0.f,0.f,0.f};

        // ---- Phase B1: layer-1 GEMM --------------------------------------
#pragma unroll 4
        for (int kb = 0; kb < 16; ++kb) {
            const int kbase = kb * 32 + koff;
            ushort8 af[2];
#pragma unroll
            for (int i = 0; i < 2; ++i) {
                const int row = i * 16 + l16;
                af[i] = *(const ushort8*)&A_lds[(row * KDIM + kbase) ^ ((row & 7) << 3)];
            }
#pragma unroll
            for (int j = 0; j < 2; ++j) {
                const int cb = wv * 2 + j;
                ushort8 bf = *(const ushort8*)&W1f[(((cb * 16 + kb) * 64) + lane) * 8];
#pragma unroll
                for (int i = 0; i < 2; ++i) {
                    acc[i][j] = __builtin_amdgcn_mfma_f32_16x16x32_bf16(
                        __builtin_bit_cast(bf16x8, af[i]),
                        __builtin_bit_cast(bf16x8, bf),
                        acc[i][j], 0, 0, 0);
                }
            }
        }

        // ---- Phase C1: H1 -> LDS lo; stage comb hi -> LDS hi --------------
        __syncthreads();
#pragma unroll
        for (int i = 0; i < 2; ++i)
#pragma unroll
            for (int j = 0; j < 2; ++j) {
                const int col = (wv * 2 + j) * 16 + l16;
#pragma unroll
                for (int rg_ = 0; rg_ < 4; ++rg_) {
                    const int row = i * 16 + (lane >> 4) * 4 + rg_;
                    A_lds[(row * KDIM + col) ^ ((row & 7) << 3)] =
                        f2bf(fmaxf(acc[i][j][rg_], 0.f));
                }
            }
        for (int i = t; i < 32 * 256 / 8; i += 512) {
            const int row = i >> 5;
            const int c8  = (i & 31) * 8;
            ushort8 v = *(const ushort8*)&comb[((size_t)(bid * 32 + row)) * KDIM + 256 + c8];
            *(ushort8*)&A_lds[(row * KDIM + 256 + c8) ^ ((row & 7) << 3)] = v;
        }
        __syncthreads();

        // ---- Phase B2: layer-2 GEMM -> out --------------------------------
#pragma unroll
        for (int i = 0; i < 2; ++i)
#pragma unroll
            for (int j = 0; j < 2; ++j) acc[i][j] = (f32x4){0.f,0.f,0.f,0.f};

#pragma unroll 4
        for (int kb = 0; kb < 16; ++kb) {
            const int kbase = kb * 32 + koff;
            ushort8 af[2];
#pragma unroll
            for (int i = 0; i < 2; ++i) {
                const int row = i * 16 + l16;
                af[i] = *(const ushort8*)&A_lds[(row * KDIM + kbase) ^ ((row & 7) << 3)];
            }
#pragma unroll
            for (int j = 0; j < 2; ++j) {
                const int cb = wv * 2 + j;
                ushort8 bf = *(const ushort8*)&W2f[(((cb * 16 + kb) * 64) + lane) * 8];
#pragma unroll
                for (int i = 0; i < 2; ++i) {
                    acc[i][j] = __builtin_amdgcn_mfma_f32_16x16x32_bf16(
                        __builtin_bit_cast(bf16x8, af[i]),
                        __builtin_bit_cast(bf16x8, bf),
                        acc[i][j], 0, 0, 0);
                }
            }
        }

#pragma unroll
        for (int i = 0; i < 2; ++i)
#pragma unroll
            for (int j = 0; j < 2; ++j) {
                const int col = (wv * 2 + j) * 16 + l16;
#pragma unroll
                for (int rg_ = 0; rg_ < 4; ++rg_) {
                    const int row = bid * 32 + i * 16 + (lane >> 4) * 4 + rg_;
                    out[(size_t)row * 256 + col] = fmaxf(acc[i][j][rg_], 0.f);
                }
            }
    }
}

// ===========================================================================
// r4-proven standalone kernels (fallback paths)
// ===========================================================================
__global__ __launch_bounds__(256)
void prep_kernel(const float* __restrict__ FM,
                 const float* __restrict__ W1, const float* __restrict__ W2,
                 unsigned short* __restrict__ FMb,
                 unsigned short* __restrict__ W1f, unsigned short* __restrict__ W2f)
{
    if (blockIdx.x < 128) {
        const int id   = blockIdx.x * 256 + threadIdx.x;
        const int lane = id & 63;
        const int grp  = id >> 6;
        const int kblk = grp & 15;
        const int cb   = (grp >> 4) & 15;
        const int mat  = grp >> 8;
        const float* W = mat ? W2 : W1;
        unsigned short* dst = mat ? W2f : W1f;
        const int col   = cb * 16 + (lane & 15);
        const int kbase = kblk * 32 + (lane >> 4) * 8;
        ushort8 v;
#pragma unroll
        for (int e = 0; e < 8; ++e) v[e] = f2bf(W[(kbase + e) * 256 + col]);
        *(ushort8*)&dst[(((cb * 16 + kblk) * 64) + lane) * 8] = v;
    } else {
        const int bid2   = blockIdx.x - 128;
        const int stride = (gridDim.x - 128) * 256;
        const int total  = NNODES * F / 8;
        for (int i = bid2 * 256 + threadIdx.x; i < total; i += stride) {
            const float4* p = (const float4*)(FM + (size_t)i * 8);
            float4 x = p[0], y = p[1];
            ushort8 v;
            v[0]=f2bf(x.x); v[1]=f2bf(x.y); v[2]=f2bf(x.z); v[3]=f2bf(x.w);
            v[4]=f2bf(y.x); v[5]=f2bf(y.y); v[6]=f2bf(y.z); v[7]=f2bf(y.w);
            *(ushort8*)&FMb[(size_t)i * 8] = v;
        }
    }
}

__global__ __launch_bounds__(256)
void wconv_kernel(const float* __restrict__ W1, const float* __restrict__ W2,
                  unsigned short* __restrict__ W1f, unsigned short* __restrict__ W2f)
{
    const int id   = blockIdx.x * 256 + threadIdx.x;
    const int lane = id & 63;
    const int grp  = id >> 6;
    const int kblk = grp & 15;
    const int cb   = (grp >> 4) & 15;
    const int mat  = grp >> 8;
    const float* W = mat ? W2 : W1;
    unsigned short* dst = mat ? W2f : W1f;
    const int col   = cb * 16 + (lane & 15);
    const int kbase = kblk * 32 + (lane >> 4) * 8;
    ushort8 v;
#pragma unroll
    for (int e = 0; e < 8; ++e) v[e] = f2bf(W[(kbase + e) * 256 + col]);
    *(ushort8*)&dst[(((cb * 16 + kblk) * 64) + lane) * 8] = v;
}

template <int TM, bool REDUCE, typename GT, int NT>
__global__ __launch_bounds__(NT, NT == 512 ? 4 : 2)
void hop_kernel(const GT* __restrict__ FMg,
                const int* __restrict__ selfIdx,
                const int* __restrict__ nbIdx,
                const unsigned short* __restrict__ Wfrag,
                unsigned short* __restrict__ outComb)
{
    __shared__ __align__(16) unsigned short A_lds[TM * KDIM];
    const int t   = threadIdx.x;
    const int bid = blockIdx.x;

    {
        const int rsub = t >> 5;
        const int c0   = (t & 31) * 8;
#pragma unroll 1
        for (int rr = 0; rr < TM; rr += NT / 32) {
            const int r  = rr + rsub;
            const int rg = bid * TM + r;
            const int self = selfIdx[rg];
            if constexpr (sizeof(GT) == 2) {
                ushort8 sv = *(const ushort8*)(FMg + (size_t)self * F + c0);
                *(ushort8*)&A_lds[(r * KDIM + c0) ^ ((r & 7) << 3)] = sv;

                float a0=0,a1=0,a2=0,a3=0,a4=0,a5=0,a6=0,a7=0;
#pragma unroll
                for (int k = 0; k < SAMP; ++k) {
                    const int idx = nbIdx[rg * SAMP + k];
                    uint4v u = __builtin_bit_cast(uint4v,
                        *(const ushort8*)(FMg + (size_t)idx * F + c0));
                    a0 += __builtin_bit_cast(float, u[0] << 16);
                    a1 += __builtin_bit_cast(float, u[0] & 0xFFFF0000u);
                    a2 += __builtin_bit_cast(float, u[1] << 16);
                    a3 += __builtin_bit_cast(float, u[1] & 0xFFFF0000u);
                    a4 += __builtin_bit_cast(float, u[2] << 16);
                    a5 += __builtin_bit_cast(float, u[2] & 0xFFFF0000u);
                    a6 += __builtin_bit_cast(float, u[3] << 16);
                    a7 += __builtin_bit_cast(float, u[3] & 0xFFFF0000u);
                }
                ushort8 m;
                m[0]=f2bf(a0*0.1f); m[1]=f2bf(a1*0.1f); m[2]=f2bf(a2*0.1f); m[3]=f2bf(a3*0.1f);
                m[4]=f2bf(a4*0.1f); m[5]=f2bf(a5*0.1f); m[6]=f2bf(a6*0.1f); m[7]=f2bf(a7*0.1f);
                *(ushort8*)&A_lds[(r * KDIM + F + c0) ^ ((r & 7) << 3)] = m;
            } else {
                const float4* sp = (const float4*)(FMg + (size_t)self * F + c0);
                float4 s0 = sp[0], s1 = sp[1];
                ushort8 v;
                v[0]=f2bf(s0.x); v[1]=f2bf(s0.y); v[2]=f2bf(s0.z); v[3]=f2bf(s0.w);
                v[4]=f2bf(s1.x); v[5]=f2bf(s1.y); v[6]=f2bf(s1.z); v[7]=f2bf(s1.w);
                *(ushort8*)&A_lds[(r * KDIM + c0) ^ ((r & 7) << 3)] = v;

                float a0=0,a1=0,a2=0,a3=0,a4=0,a5=0,a6=0,a7=0;
#pragma unroll
                for (int k = 0; k < SAMP; ++k) {
                    const int idx = nbIdx[rg * SAMP + k];
                    const float4* np_ = (const float4*)(FMg + (size_t)idx * F + c0);
                    float4 n0 = np_[0], n1 = np_[1];
                    a0+=n0.x; a1+=n0.y; a2+=n0.z; a3+=n0.w;
                    a4+=n1.x; a5+=n1.y; a6+=n1.z; a7+=n1.w;
                }
                ushort8 m;
                m[0]=f2bf(a0*0.1f); m[1]=f2bf(a1*0.1f); m[2]=f2bf(a2*0.1f); m[3]=f2bf(a3*0.1f);
                m[4]=f2bf(a4*0.1f); m[5]=f2bf(a5*0.1f); m[6]=f2bf(a6*0.1f); m[7]=f2bf(a7*0.1f);
                *(ushort8*)&A_lds[(r * KDIM + F + c0) ^ ((r & 7) << 3)] = m;
            }
        }
    }
    __syncthreads();

    constexpr int RM  = TM / 16;
    constexpr int CPW = 1024 / NT;
    const int wv   = t >> 6;
    const int lane = t & 63;
    const int l16  = lane & 15;
    const int koff = (lane >> 4) * 8;

    f32x4 acc[RM][CPW];
#pragma unroll
    for (int i = 0; i < RM; ++i)
#pragma unroll
        for (int j = 0; j < CPW; ++j) acc[i][j] = (f32x4){0.f, 0.f, 0.f, 0.f};

#pragma unroll 4
    for (int kb = 0; kb < 16; ++kb) {
        const int kbase = kb * 32 + koff;
        ushort8 af[RM];
#pragma unroll
        for (int i = 0; i < RM; ++i) {
            const int row = i * 16 + l16;
            af[i] = *(const ushort8*)&A_lds[(row * KDIM + kbase) ^ ((row & 7) << 3)];
        }
#pragma unroll
        for (int j = 0; j < CPW; ++j) {
            const int cb = wv * CPW + j;
            ushort8 bf = *(const ushort8*)&Wfrag[(((cb * 16 + kb) * 64) + lane) * 8];
#pragma unroll
            for (int i = 0; i < RM; ++i) {
                acc[i][j] = __builtin_amdgcn_mfma_f32_16x16x32_bf16(
                    __builtin_bit_cast(bf16x8, af[i]),
                    __builtin_bit_cast(bf16x8, bf),
                    acc[i][j], 0, 0, 0);
            }
        }
    }

    if (REDUCE) {
        __syncthreads();
        float* C_lds = (float*)A_lds;
#pragma unroll
        for (int i = 0; i < RM; ++i)
#pragma unroll
            for (int j = 0; j < CPW; ++j) {
                const int col = (wv * CPW + j) * 16 + l16;
#pragma unroll
                for (int rg_ = 0; rg_ < 4; ++rg_) {
                    const int row = i * 16 + (lane >> 4) * 4 + rg_;
                    C_lds[row * 256 + col] = fmaxf(acc[i][j][rg_], 0.f);
                }
            }
        __syncthreads();
        constexpr int GH = NT / 256;
        constexpr int GPT = (TM / 10) / GH;
        const int c  = t & 255;
        const int gh = t >> 8;
#pragma unroll
        for (int g2 = 0; g2 < GPT; ++g2) {
            const int g = gh * GPT + g2;
            float s = 0.f;
#pragma unroll
            for (int j = 0; j < SAMP; ++j) s += C_lds[(g * SAMP + j) * 256 + c];
            outComb[((size_t)(bid * (TM / 10) + g)) * KDIM + F + c] = f2bf(s * 0.1f);
        }
    } else {
#pragma unroll
        for (int i = 0; i < RM; ++i)
#pragma unroll
            for (int j = 0; j < CPW; ++j) {
                const int col = (wv * CPW + j) * 16 + l16;
#pragma unroll
                for (int rg_ = 0; rg_ < 4; ++rg_) {
                    const int row = bid * TM + i * 16 + (lane >> 4) * 4 + rg_;
                    outComb[(size_t)row * KDIM + col] = f2bf(fmaxf(acc[i][j][rg_], 0.f));
                }
            }
    }
}

__global__ __launch_bounds__(256)
void root_kernel(const unsigned short* __restrict__ FMb,
                 const int* __restrict__ forest0,
                 const int* __restrict__ forest1,
                 const unsigned short* __restrict__ W1f,
                 const unsigned short* __restrict__ W2f,
                 const unsigned short* __restrict__ comb,
                 float* __restrict__ out)
{
    constexpr int TM = 32;
    __shared__ __align__(16) unsigned short A_lds[TM * KDIM];
    const int t   = threadIdx.x;
    const int bid = blockIdx.x;

    {
        const int rsub = t >> 5;
        const int c0   = (t & 31) * 8;
#pragma unroll 1
        for (int rr = 0; rr < TM; rr += 8) {
            const int r  = rr + rsub;
            const int rg = bid * TM + r;
            const int self = forest0[rg];
            ushort8 sv = *(const ushort8*)(FMb + (size_t)self * F + c0);
            *(ushort8*)&A_lds[(r * KDIM + c0) ^ ((r & 7) << 3)] = sv;

            float a0=0,a1=0,a2=0,a3=0,a4=0,a5=0,a6=0,a7=0;
#pragma unroll
            for (int k = 0; k < SAMP; ++k) {
                const int idx = forest1[rg * SAMP + k];
                uint4v u = __builtin_bit_cast(uint4v,
                    *(const ushort8*)(FMb + (size_t)idx * F + c0));
                a0 += __builtin_bit_cast(float, u[0] << 16);
                a1 += __builtin_bit_cast(float, u[0] & 0xFFFF0000u);
                a2 += __builtin_bit_cast(float, u[1] << 16);
                a3 += __builtin_bit_cast(float, u[1] & 0xFFFF0000u);
                a4 += __builtin_bit_cast(float, u[2] << 16);
                a5 += __builtin_bit_cast(float, u[2] & 0xFFFF0000u);
                a6 += __builtin_bit_cast(float, u[3] << 16);
                a7 += __builtin_bit_cast(float, u[3] & 0xFFFF0000u);
            }
            ushort8 m;
            m[0]=f2bf(a0*0.1f); m[1]=f2bf(a1*0.1f); m[2]=f2bf(a2*0.1f); m[3]=f2bf(a3*0.1f);
            m[4]=f2bf(a4*0.1f); m[5]=f2bf(a5*0.1f); m[6]=f2bf(a6*0.1f); m[7]=f2bf(a7*0.1f);
            *(ushort8*)&A_lds[(r * KDIM + F + c0) ^ ((r & 7) << 3)] = m;
        }
    }
    __syncthreads();

    constexpr int RM = TM / 16;
    const int wv = t >> 6, lane = t & 63, l16 = lane & 15, koff = (lane >> 4) * 8;

    f32x4 acc[RM][4];
#pragma unroll
    for (int i = 0; i < RM; ++i)
#pragma unroll
        for (int j = 0; j < 4; ++j) acc[i][j] = (f32x4){0.f, 0.f, 0.f, 0.f};

#pragma unroll 4
    for (int kb = 0; kb < 16; ++kb) {
        const int kbase = kb * 32 + koff;
        ushort8 af[RM];
#pragma unroll
        for (int i = 0; i < RM; ++i) {
            const int row = i * 16 + l16;
            af[i] = *(const ushort8*)&A_lds[(row * KDIM + kbase) ^ ((row & 7) << 3)];
        }
#pragma unroll
        for (int j = 0; j < 4; ++j) {
            const int cb = wv * 4 + j;
            ushort8 bf = *(const ushort8*)&W1f[(((cb * 16 + kb) * 64) + lane) * 8];
#pragma unroll
            for (int i = 0; i < RM; ++i) {
                acc[i][j] = __builtin_amdgcn_mfma_f32_16x16x32_bf16(
                    __builtin_bit_cast(bf16x8, af[i]),
                    __builtin_bit_cast(bf16x8, bf),
                    acc[i][j], 0, 0, 0);
            }
        }
    }

    __syncthreads();
#pragma unroll
    for (int i = 0; i < RM; ++i)
#pragma unroll
        for (int j = 0; j < 4; ++j) {
            const int col = (wv * 4 + j) * 16 + l16;
#pragma unroll
            for (int rg_ = 0; rg_ < 4; ++rg_) {
                const int row = i * 16 + (lane >> 4) * 4 + rg_;
                A_lds[(row * KDIM + col) ^ ((row & 7) << 3)] =
                    f2bf(fmaxf(acc[i][j][rg_], 0.f));
            }
        }
    for (int i = t; i < TM * 256 / 8; i += 256) {
        const int row = i >> 5;
        const int c8  = (i & 31) * 8;
        ushort8 v = *(const ushort8*)&comb[((size_t)(bid * TM + row)) * KDIM + 256 + c8];
        *(ushort8*)&A_lds[(row * KDIM + 256 + c8) ^ ((row & 7) << 3)] = v;
    }
    __syncthreads();

#pragma unroll
    for (int i = 0; i < RM; ++i)
#pragma unroll
        for (int j = 0; j < 4; ++j) acc[i][j] = (f32x4){0.f, 0.f, 0.f, 0.f};

#pragma unroll 4
    for (int kb = 0; kb < 16; ++kb) {
        const int kbase = kb * 32 + koff;
        ushort8 af[RM];
#pragma unroll
        for (int i = 0; i < RM; ++i) {
            const int row = i * 16 + l16;
            af[i] = *(const ushort8*)&A_lds[(row * KDIM + kbase) ^ ((row & 7) << 3)];
        }
#pragma unroll
        for (int j = 0; j < 4; ++j) {
            const int cb = wv * 4 + j;
            ushort8 bf = *(const ushort8*)&W2f[(((cb * 16 + kb) * 64) + lane) * 8];
#pragma unroll
            for (int i = 0; i < RM; ++i) {
                acc[i][j] = __builtin_amdgcn_mfma_f32_16x16x32_bf16(
                    __builtin_bit_cast(bf16x8, af[i]),
                    __builtin_bit_cast(bf16x8, bf),
                    acc[i][j], 0, 0, 0);
            }
        }
    }

#pragma unroll
    for (int i = 0; i < RM; ++i)
#pragma unroll
        for (int j = 0; j < 4; ++j) {
            const int col = (wv * 4 + j) * 16 + l16;
#pragma unroll
            for (int rg_ = 0; rg_ < 4; ++rg_) {
                const int row = bid * TM + i * 16 + (lane >> 4) * 4 + rg_;
                out[(size_t)row * 256 + col] = fmaxf(acc[i][j][rg_], 0.f);
            }
        }
}

__global__ __launch_bounds__(256)
void gemm2_kernel(const unsigned short* __restrict__ comb,
                  const unsigned short* __restrict__ Wfrag,
                  float* __restrict__ out)
{
    constexpr int TM = 32;
    __shared__ __align__(16) unsigned short B_lds[TM * KDIM];
    const int t   = threadIdx.x;
    const int bid = blockIdx.x;

    for (int i = t; i < TM * KDIM / 8; i += 256) {
        const int row = i >> 6;
        const int c8  = (i & 63) * 8;
        ushort8 v = *(const ushort8*)&comb[((size_t)(bid * TM + row)) * KDIM + c8];
        *(ushort8*)&B_lds[(row * KDIM + c8) ^ ((row & 7) << 3)] = v;
    }
    __syncthreads();

    constexpr int RM = TM / 16;
    const int wv = t >> 6, lane = t & 63, l16 = lane & 15, koff = (lane >> 4) * 8;
    f32x4 acc[RM][4];
#pragma unroll
    for (int i = 0; i < RM; ++i)
#pragma unroll
        for (int j = 0; j < 4; ++j) acc[i][j] = (f32x4){0.f, 0.f, 0.f, 0.f};

#pragma unroll 4
    for (int kb = 0; kb < 16; ++kb) {
        const int kbase = kb * 32 + koff;
        ushort8 af[RM];
#pragma unroll
        for (int i = 0; i < RM; ++i) {
            const int row = i * 16 + l16;
            af[i] = *(const ushort8*)&B_lds[(row * KDIM + kbase) ^ ((row & 7) << 3)];
        }
#pragma unroll
        for (int j = 0; j < 4; ++j) {
            const int cb = wv * 4 + j;
            ushort8 bf = *(const ushort8*)&Wfrag[(((cb * 16 + kb) * 64) + lane) * 8];
#pragma unroll
            for (int i = 0; i < RM; ++i) {
                acc[i][j] = __builtin_amdgcn_mfma_f32_16x16x32_bf16(
                    __builtin_bit_cast(bf16x8, af[i]),
                    __builtin_bit_cast(bf16x8, bf),
                    acc[i][j], 0, 0, 0);
            }
        }
    }

#pragma unroll
    for (int i = 0; i < RM; ++i)
#pragma unroll
        for (int j = 0; j < 4; ++j) {
            const int col = (wv * 4 + j) * 16 + l16;
#pragma unroll
            for (int rg_ = 0; rg_ < 4; ++rg_) {
                const int row = bid * TM + i * 16 + (lane >> 4) * 4 + rg_;
                out[(size_t)row * 256 + col] = fmaxf(acc[i][j][rg_], 0.f);
            }
        }
}

// ---------------------------------------------------------------------------
extern "C" void kernel_launch(void* const* d_in, const int* in_sizes, int n_in,
                              void* d_out, int out_size, void* d_ws, size_t ws_size,
                              hipStream_t stream)
{
    const int*   forest0 = (const int*)d_in[0];    // [8192]
    const int*   forest1 = (const int*)d_in[1];    // [8192*10]
    const int*   forest2 = (const int*)d_in[2];    // [81920*10]
    const float* FM      = (const float*)d_in[3];  // [100000*256]
    const float* W1      = (const float*)d_in[4];  // [512*256]
    const float* W2      = (const float*)d_in[5];  // [512*256]
    float*       out     = (float*)d_out;          // [8192*256]

    const size_t fmbElems  = (size_t)NNODES * F;
    const size_t wElems    = (size_t)512 * 256;
    const size_t combElems = (size_t)NROOTS * KDIM;
    const size_t needBytes = (fmbElems + 2 * wElems + combElems) * sizeof(unsigned short);

    if (ws_size >= needBytes) {
        unsigned short* FMb  = (unsigned short*)d_ws;
        unsigned short* W1f  = FMb + fmbElems;
        unsigned short* W2f  = W1f + wElems;
        unsigned short* comb = W2f + wElems;

        // one-time capability check (host-side queries; capture-safe)
        static int coopOK = -1;
        if (coopOK < 0) {
            int dev = 0;
            hipGetDevice(&dev);
            int attr = 0;
            hipDeviceGetAttribute(&attr, hipDeviceAttributeCooperativeLaunch, dev);
            int maxB = 0;
            hipError_t oe = hipOccupancyMaxActiveBlocksPerMultiprocessor(
                &maxB, mega_kernel, 512, 0);
            coopOK = (attr != 0 && oe == hipSuccess && maxB >= 2) ? 1 : 0;
        }

        bool launched = false;
        if (coopOK == 1) {
            void* args[] = {
                (void*)&FM, (void*)&W1, (void*)&W2,
                (void*)&forest0, (void*)&forest1, (void*)&forest2,
                (void*)&FMb, (void*)&W1f, (void*)&W2f, (void*)&comb, (void*)&out
            };
            hipError_t e = hipLaunchCooperativeKernel(
                reinterpret_cast<void*>(mega_kernel),
                dim3(512), dim3(512), args, 0, stream);
            launched = (e == hipSuccess);
            if (!launched) coopOK = 0;     // don't retry on later calls
        }

        if (!launched) {
            // exact r4 path (proven 117.8 us)
            prep_kernel<<<dim3(128 + 2048), dim3(256), 0, stream>>>(
                FM, W1, W2, FMb, W1f, W2f);
            hop_kernel<80, true, unsigned short, 512>
                <<<dim3(HOP1ROWS / 80), dim3(512), 0, stream>>>(
                FMb, forest1, forest2, W1f, comb);
            root_kernel<<<dim3(NROOTS / 32), dim3(256), 0, stream>>>(
                FMb, forest0, forest1, W1f, W2f, comb, out);
        }
    } else {
        // fallback: original f32-gather path (~8.6 MB workspace)
        unsigned short* W1f  = (unsigned short*)d_ws;
        unsigned short* W2f  = W1f + wElems;
        unsigned short* comb = W2f + wElems;

        wconv_kernel<<<dim3(128), dim3(256), 0, stream>>>(W1, W2, W1f, W2f);
        hop_kernel<80, true, float, 256>
            <<<dim3(HOP1ROWS / 80), dim3(256), 0, stream>>>(
            FM, forest1, forest2, W1f, comb);
        hop_kernel<32, false, float, 256>
            <<<dim3(NROOTS / 32), dim3(256), 0, stream>>>(
            FM, forest0, forest1, W1f, comb);
        gemm2_kernel<<<dim3(NROOTS / 32), dim3(256), 0, stream>>>(comb, W2f, out);
    }
}

// Round 7
// 111.436 us; speedup vs baseline: 1.1272x; 1.0611x over previous
//
#include <hip/hip_runtime.h>
#include <hip/hip_bf16.h>

// Problem constants (from reference)
#define F        256
#define NNODES   100000
#define NROOTS   8192
#define SAMP     10
#define KDIM     512        // 2*F concat width
#define HOP1ROWS (NROOTS * SAMP)   // 81920

typedef __bf16   bf16x8  __attribute__((ext_vector_type(8)));
typedef unsigned short ushort8 __attribute__((ext_vector_type(8)));
typedef unsigned int   uint4v  __attribute__((ext_vector_type(4)));
typedef float    f32x4   __attribute__((ext_vector_type(4)));

__device__ __forceinline__ unsigned short f2bf(float f) {
    unsigned int u = __builtin_bit_cast(unsigned int, f);
    u += 0x7FFFu + ((u >> 16) & 1u);      // round-to-nearest-even
    return (unsigned short)(u >> 16);
}

// ---------------------------------------------------------------------------
// prep_kernel: fused weight conversion + feature-matrix bf16 conversion.
// Blocks [0,128): W1/W2 f32 -> bf16 B-fragment order
//   frag[((cb*16 + kblk)*64 + lane)*8 + e] = W[k][col]
//   col = cb*16 + (lane&15),  k = kblk*32 + (lane>>4)*8 + e
// Blocks [128, 128+2048): FM f32 [100000][256] -> FMb bf16 (grid-stride)
// ---------------------------------------------------------------------------
__global__ __launch_bounds__(256)
void prep_kernel(const float* __restrict__ FM,
                 const float* __restrict__ W1, const float* __restrict__ W2,
                 unsigned short* __restrict__ FMb,
                 unsigned short* __restrict__ W1f, unsigned short* __restrict__ W2f)
{
    if (blockIdx.x < 128) {
        const int id   = blockIdx.x * 256 + threadIdx.x;   // 32768 total
        const int lane = id & 63;
        const int grp  = id >> 6;          // 512 groups
        const int kblk = grp & 15;
        const int cb   = (grp >> 4) & 15;
        const int mat  = grp >> 8;         // 0 -> W1, 1 -> W2
        const float* W = mat ? W2 : W1;
        unsigned short* dst = mat ? W2f : W1f;

        const int col   = cb * 16 + (lane & 15);
        const int kbase = kblk * 32 + (lane >> 4) * 8;
        ushort8 v;
#pragma unroll
        for (int e = 0; e < 8; ++e) v[e] = f2bf(W[(kbase + e) * 256 + col]);
        *(ushort8*)&dst[(((cb * 16 + kblk) * 64) + lane) * 8] = v;
    } else {
        const int bid2   = blockIdx.x - 128;
        const int stride = (gridDim.x - 128) * 256;
        const int total  = NNODES * F / 8;             // 3,200,000 groups of 8
        for (int i = bid2 * 256 + threadIdx.x; i < total; i += stride) {
            const float4* p = (const float4*)(FM + (size_t)i * 8);
            float4 x = p[0], y = p[1];
            ushort8 v;
            v[0]=f2bf(x.x); v[1]=f2bf(x.y); v[2]=f2bf(x.z); v[3]=f2bf(x.w);
            v[4]=f2bf(y.x); v[5]=f2bf(y.y); v[6]=f2bf(y.z); v[7]=f2bf(y.w);
            *(ushort8*)&FMb[(size_t)i * 8] = v;
        }
    }
}

// ---------------------------------------------------------------------------
// Standalone wconv (fallback path only)
// ---------------------------------------------------------------------------
__global__ __launch_bounds__(256)
void wconv_kernel(const float* __restrict__ W1, const float* __restrict__ W2,
                  unsigned short* __restrict__ W1f, unsigned short* __restrict__ W2f)
{
    const int id   = blockIdx.x * 256 + threadIdx.x;   // 32768 total
    const int lane = id & 63;
    const int grp  = id >> 6;
    const int kblk = grp & 15;
    const int cb   = (grp >> 4) & 15;
    const int mat  = grp >> 8;
    const float* W = mat ? W2 : W1;
    unsigned short* dst = mat ? W2f : W1f;

    const int col   = cb * 16 + (lane & 15);
    const int kbase = kblk * 32 + (lane >> 4) * 8;
    ushort8 v;
#pragma unroll
    for (int e = 0; e < 8; ++e) v[e] = f2bf(W[(kbase + e) * 256 + col]);
    *(ushort8*)&dst[(((cb * 16 + kblk) * 64) + lane) * 8] = v;
}

// ---------------------------------------------------------------------------
// Fused gather + mean + layer-1 GEMM (+ optional group-of-10 mean reduce).
// GT = unsigned short (bf16 table) or float (fallback).
// NT = threads per block. r4-proven: NT=512, LDS 80KB -> 2 blocks/CU,
// 16 waves/CU, VGPR 60 (gather-MLP sweet spot; NT=1024 clips VGPR - r5).
// XNB (REDUCE path only): after Phase A, also emit per-root mean of the 10
// SELF rows (bit-identical to the gather+mean the root kernel would do) to
// xnbOut[root][256] - saves root's 81920-row random re-gather.
// ---------------------------------------------------------------------------
template <int TM, bool REDUCE, typename GT, int NT, bool XNB>
__global__ __launch_bounds__(NT, NT == 512 ? 4 : 2)
void hop_kernel(const GT* __restrict__ FMg,
                const int* __restrict__ selfIdx,
                const int* __restrict__ nbIdx,
                const unsigned short* __restrict__ Wfrag,
                unsigned short* __restrict__ outComb,
                unsigned short* __restrict__ xnbOut)
{
    __shared__ __align__(16) unsigned short A_lds[TM * KDIM];   // bf16 tile, swizzled
    const int t   = threadIdx.x;
    const int bid = blockIdx.x;

    // ---- Phase A: gather self + mean(10 neighbors) into LDS bf16 ----------
    // (byte-identical to the r4-proven loop)
    {
        const int rsub = t >> 5;
        const int c0   = (t & 31) * 8;    // 8 elements per thread per row
#pragma unroll 1
        for (int rr = 0; rr < TM; rr += NT / 32) {
            const int r  = rr + rsub;
            const int rg = bid * TM + r;
            const int self = selfIdx[rg];
            if constexpr (sizeof(GT) == 2) {
                ushort8 sv = *(const ushort8*)(FMg + (size_t)self * F + c0);
                *(ushort8*)&A_lds[(r * KDIM + c0) ^ ((r & 7) << 3)] = sv;

                float a0=0,a1=0,a2=0,a3=0,a4=0,a5=0,a6=0,a7=0;
#pragma unroll
                for (int k = 0; k < SAMP; ++k) {
                    const int idx = nbIdx[rg * SAMP + k];
                    uint4v u = __builtin_bit_cast(uint4v,
                        *(const ushort8*)(FMg + (size_t)idx * F + c0));
                    a0 += __builtin_bit_cast(float, u[0] << 16);
                    a1 += __builtin_bit_cast(float, u[0] & 0xFFFF0000u);
                    a2 += __builtin_bit_cast(float, u[1] << 16);
                    a3 += __builtin_bit_cast(float, u[1] & 0xFFFF0000u);
                    a4 += __builtin_bit_cast(float, u[2] << 16);
                    a5 += __builtin_bit_cast(float, u[2] & 0xFFFF0000u);
                    a6 += __builtin_bit_cast(float, u[3] << 16);
                    a7 += __builtin_bit_cast(float, u[3] & 0xFFFF0000u);
                }
                ushort8 m;
                m[0]=f2bf(a0*0.1f); m[1]=f2bf(a1*0.1f); m[2]=f2bf(a2*0.1f); m[3]=f2bf(a3*0.1f);
                m[4]=f2bf(a4*0.1f); m[5]=f2bf(a5*0.1f); m[6]=f2bf(a6*0.1f); m[7]=f2bf(a7*0.1f);
                *(ushort8*)&A_lds[(r * KDIM + F + c0) ^ ((r & 7) << 3)] = m;
            } else {
                const float4* sp = (const float4*)(FMg + (size_t)self * F + c0);
                float4 s0 = sp[0], s1 = sp[1];
                ushort8 v;
                v[0]=f2bf(s0.x); v[1]=f2bf(s0.y); v[2]=f2bf(s0.z); v[3]=f2bf(s0.w);
                v[4]=f2bf(s1.x); v[5]=f2bf(s1.y); v[6]=f2bf(s1.z); v[7]=f2bf(s1.w);
                *(ushort8*)&A_lds[(r * KDIM + c0) ^ ((r & 7) << 3)] = v;

                float a0=0,a1=0,a2=0,a3=0,a4=0,a5=0,a6=0,a7=0;
#pragma unroll
                for (int k = 0; k < SAMP; ++k) {
                    const int idx = nbIdx[rg * SAMP + k];
                    const float4* np_ = (const float4*)(FMg + (size_t)idx * F + c0);
                    float4 n0 = np_[0], n1 = np_[1];
                    a0+=n0.x; a1+=n0.y; a2+=n0.z; a3+=n0.w;
                    a4+=n1.x; a5+=n1.y; a6+=n1.z; a7+=n1.w;
                }
                ushort8 m;
                m[0]=f2bf(a0*0.1f); m[1]=f2bf(a1*0.1f); m[2]=f2bf(a2*0.1f); m[3]=f2bf(a3*0.1f);
                m[4]=f2bf(a4*0.1f); m[5]=f2bf(a5*0.1f); m[6]=f2bf(a6*0.1f); m[7]=f2bf(a7*0.1f);
                *(ushort8*)&A_lds[(r * KDIM + F + c0) ^ ((r & 7) << 3)] = m;
            }
        }
    }
    __syncthreads();

    // ---- XNB: per-root mean of the 10 SELF rows -> xnb table --------------
    // Read-only on A_lds (as is Phase B) -> no extra barrier needed. The
    // barrier before the C_lds overwrite orders these reads vs the overwrite.
    if constexpr (XNB) {
        if (t < 256) {                        // 8 groups x 32 ushort8 chunks
            const int g  = t >> 5;            // root group 0..7 (TM==80)
            const int c0 = (t & 31) * 8;
            float a0=0,a1=0,a2=0,a3=0,a4=0,a5=0,a6=0,a7=0;
#pragma unroll
            for (int j = 0; j < SAMP; ++j) {
                const int row = g * SAMP + j;
                uint4v u = __builtin_bit_cast(uint4v,
                    *(const ushort8*)&A_lds[(row * KDIM + c0) ^ ((row & 7) << 3)]);
                a0 += __builtin_bit_cast(float, u[0] << 16);
                a1 += __builtin_bit_cast(float, u[0] & 0xFFFF0000u);
                a2 += __builtin_bit_cast(float, u[1] << 16);
                a3 += __builtin_bit_cast(float, u[1] & 0xFFFF0000u);
                a4 += __builtin_bit_cast(float, u[2] << 16);
                a5 += __builtin_bit_cast(float, u[2] & 0xFFFF0000u);
                a6 += __builtin_bit_cast(float, u[3] << 16);
                a7 += __builtin_bit_cast(float, u[3] & 0xFFFF0000u);
            }
            ushort8 m;
            m[0]=f2bf(a0*0.1f); m[1]=f2bf(a1*0.1f); m[2]=f2bf(a2*0.1f); m[3]=f2bf(a3*0.1f);
            m[4]=f2bf(a4*0.1f); m[5]=f2bf(a5*0.1f); m[6]=f2bf(a6*0.1f); m[7]=f2bf(a7*0.1f);
            *(ushort8*)&xnbOut[((size_t)(bid * 8 + g)) * F + c0] = m;
        }
    }

    // ---- Phase B: MFMA GEMM [TM,512] x [512,256] --------------------------
    constexpr int RM  = TM / 16;
    constexpr int CPW = 1024 / NT;    // col-blocks of 16 per wave
    const int wv   = t >> 6;
    const int lane = t & 63;
    const int l16  = lane & 15;
    const int koff = (lane >> 4) * 8;

    f32x4 acc[RM][CPW];
#pragma unroll
    for (int i = 0; i < RM; ++i)
#pragma unroll
        for (int j = 0; j < CPW; ++j) acc[i][j] = (f32x4){0.f, 0.f, 0.f, 0.f};

#pragma unroll 4
    for (int kb = 0; kb < 16; ++kb) {
        const int kbase = kb * 32 + koff;
        ushort8 af[RM];
#pragma unroll
        for (int i = 0; i < RM; ++i) {
            const int row = i * 16 + l16;
            af[i] = *(const ushort8*)&A_lds[(row * KDIM + kbase) ^ ((row & 7) << 3)];
        }
#pragma unroll
        for (int j = 0; j < CPW; ++j) {
            const int cb = wv * CPW + j;
            ushort8 bf = *(const ushort8*)&Wfrag[(((cb * 16 + kb) * 64) + lane) * 8];
#pragma unroll
            for (int i = 0; i < RM; ++i) {
                acc[i][j] = __builtin_amdgcn_mfma_f32_16x16x32_bf16(
                    __builtin_bit_cast(bf16x8, af[i]),
                    __builtin_bit_cast(bf16x8, bf),
                    acc[i][j], 0, 0, 0);
            }
        }
    }

    // ---- Phase C: epilogue ------------------------------------------------
    if (REDUCE) {
        __syncthreads();                       // all A_lds reads (B + XNB) done
        float* C_lds = (float*)A_lds;          // reuse as f32 [TM][256]
#pragma unroll
        for (int i = 0; i < RM; ++i)
#pragma unroll
            for (int j = 0; j < CPW; ++j) {
                const int col = (wv * CPW + j) * 16 + l16;
#pragma unroll
                for (int rg_ = 0; rg_ < 4; ++rg_) {
                    const int row = i * 16 + (lane >> 4) * 4 + rg_;
                    C_lds[row * 256 + col] = fmaxf(acc[i][j][rg_], 0.f);
                }
            }
        __syncthreads();
        constexpr int GH = NT / 256;            // column-halves of threads
        constexpr int GPT = (TM / 10) / GH;     // root groups per thread
        const int c  = t & 255;
        const int gh = t >> 8;
#pragma unroll
        for (int g2 = 0; g2 < GPT; ++g2) {
            const int g = gh * GPT + g2;
            float s = 0.f;
#pragma unroll
            for (int j = 0; j < SAMP; ++j) s += C_lds[(g * SAMP + j) * 256 + c];
            outComb[((size_t)(bid * (TM / 10) + g)) * KDIM + F + c] = f2bf(s * 0.1f);
        }
    } else {
#pragma unroll
        for (int i = 0; i < RM; ++i)
#pragma unroll
            for (int j = 0; j < CPW; ++j) {
                const int col = (wv * CPW + j) * 16 + l16;
#pragma unroll
                for (int rg_ = 0; rg_ < 4; ++rg_) {
                    const int row = bid * TM + i * 16 + (lane >> 4) * 4 + rg_;
                    outComb[(size_t)row * KDIM + col] = f2bf(fmaxf(acc[i][j][rg_], 0.f));
                }
            }
    }
}

// ---------------------------------------------------------------------------
// root_kernel: fused hop32 + layer-2 GEMM.
// NBPRE=true : neighbor-mean row comes from xnb (bit-identical to the gather
//              path: same bf16 inputs, same sum order, same f2bf rounding).
// NBPRE=false: original gather+mean (r4 path).
// ---------------------------------------------------------------------------
template <bool NBPRE>
__global__ __launch_bounds__(256)
void root_kernel(const unsigned short* __restrict__ FMb,
                 const int* __restrict__ forest0,
                 const int* __restrict__ forest1,
                 const unsigned short* __restrict__ W1f,
                 const unsigned short* __restrict__ W2f,
                 const unsigned short* __restrict__ comb,   // hop80 half lives here
                 const unsigned short* __restrict__ nbPre,  // xnb table (NBPRE)
                 float* __restrict__ out)
{
    constexpr int TM = 32;
    __shared__ __align__(16) unsigned short A_lds[TM * KDIM];
    const int t   = threadIdx.x;
    const int bid = blockIdx.x;

    // ---- Phase A: self gather + neighbor-mean row -------------------------
    {
        const int rsub = t >> 5;
        const int c0   = (t & 31) * 8;
#pragma unroll 1
        for (int rr = 0; rr < TM; rr += 8) {
            const int r  = rr + rsub;
            const int rg = bid * TM + r;
            const int self = forest0[rg];
            ushort8 sv = *(const ushort8*)(FMb + (size_t)self * F + c0);
            *(ushort8*)&A_lds[(r * KDIM + c0) ^ ((r & 7) << 3)] = sv;

            if constexpr (NBPRE) {
                ushort8 pv = *(const ushort8*)(nbPre + (size_t)rg * F + c0);
                *(ushort8*)&A_lds[(r * KDIM + F + c0) ^ ((r & 7) << 3)] = pv;
            } else {
                float a0=0,a1=0,a2=0,a3=0,a4=0,a5=0,a6=0,a7=0;
#pragma unroll
                for (int k = 0; k < SAMP; ++k) {
                    const int idx = forest1[rg * SAMP + k];
                    uint4v u = __builtin_bit_cast(uint4v,
                        *(const ushort8*)(FMb + (size_t)idx * F + c0));
                    a0 += __builtin_bit_cast(float, u[0] << 16);
                    a1 += __builtin_bit_cast(float, u[0] & 0xFFFF0000u);
                    a2 += __builtin_bit_cast(float, u[1] << 16);
                    a3 += __builtin_bit_cast(float, u[1] & 0xFFFF0000u);
                    a4 += __builtin_bit_cast(float, u[2] << 16);
                    a5 += __builtin_bit_cast(float, u[2] & 0xFFFF0000u);
                    a6 += __builtin_bit_cast(float, u[3] << 16);
                    a7 += __builtin_bit_cast(float, u[3] & 0xFFFF0000u);
                }
                ushort8 m;
                m[0]=f2bf(a0*0.1f); m[1]=f2bf(a1*0.1f); m[2]=f2bf(a2*0.1f); m[3]=f2bf(a3*0.1f);
                m[4]=f2bf(a4*0.1f); m[5]=f2bf(a5*0.1f); m[6]=f2bf(a6*0.1f); m[7]=f2bf(a7*0.1f);
                *(ushort8*)&A_lds[(r * KDIM + F + c0) ^ ((r & 7) << 3)] = m;
            }
        }
    }
    __syncthreads();

    constexpr int RM = TM / 16;
    const int wv = t >> 6, lane = t & 63, l16 = lane & 15, koff = (lane >> 4) * 8;

    f32x4 acc[RM][4];
#pragma unroll
    for (int i = 0; i < RM; ++i)
#pragma unroll
        for (int j = 0; j < 4; ++j) acc[i][j] = (f32x4){0.f, 0.f, 0.f, 0.f};

    // ---- Phase B1: layer-1 GEMM ------------------------------------------
#pragma unroll 4
    for (int kb = 0; kb < 16; ++kb) {
        const int kbase = kb * 32 + koff;
        ushort8 af[RM];
#pragma unroll
        for (int i = 0; i < RM; ++i) {
            const int row = i * 16 + l16;
            af[i] = *(const ushort8*)&A_lds[(row * KDIM + kbase) ^ ((row & 7) << 3)];
        }
#pragma unroll
        for (int j = 0; j < 4; ++j) {
            const int cb = wv * 4 + j;
            ushort8 bf = *(const ushort8*)&W1f[(((cb * 16 + kb) * 64) + lane) * 8];
#pragma unroll
            for (int i = 0; i < RM; ++i) {
                acc[i][j] = __builtin_amdgcn_mfma_f32_16x16x32_bf16(
                    __builtin_bit_cast(bf16x8, af[i]),
                    __builtin_bit_cast(bf16x8, bf),
                    acc[i][j], 0, 0, 0);
            }
        }
    }

    // ---- Phase C1: H1 -> LDS lo half; stage hop80 half -> LDS hi half -----
    __syncthreads();                           // all B1 reads of A_lds done
#pragma unroll
    for (int i = 0; i < RM; ++i)
#pragma unroll
        for (int j = 0; j < 4; ++j) {
            const int col = (wv * 4 + j) * 16 + l16;
#pragma unroll
            for (int rg_ = 0; rg_ < 4; ++rg_) {
                const int row = i * 16 + (lane >> 4) * 4 + rg_;
                A_lds[(row * KDIM + col) ^ ((row & 7) << 3)] =
                    f2bf(fmaxf(acc[i][j][rg_], 0.f));
            }
        }
    for (int i = t; i < TM * 256 / 8; i += 256) {     // 4 ushort8 per thread
        const int row = i >> 5;
        const int c8  = (i & 31) * 8;
        ushort8 v = *(const ushort8*)&comb[((size_t)(bid * TM + row)) * KDIM + 256 + c8];
        *(ushort8*)&A_lds[(row * KDIM + 256 + c8) ^ ((row & 7) << 3)] = v;
    }
    __syncthreads();

    // ---- Phase B2: layer-2 GEMM ------------------------------------------
#pragma unroll
    for (int i = 0; i < RM; ++i)
#pragma unroll
        for (int j = 0; j < 4; ++j) acc[i][j] = (f32x4){0.f, 0.f, 0.f, 0.f};

#pragma unroll 4
    for (int kb = 0; kb < 16; ++kb) {
        const int kbase = kb * 32 + koff;
        ushort8 af[RM];
#pragma unroll
        for (int i = 0; i < RM; ++i) {
            const int row = i * 16 + l16;
            af[i] = *(const ushort8*)&A_lds[(row * KDIM + kbase) ^ ((row & 7) << 3)];
        }
#pragma unroll
        for (int j = 0; j < 4; ++j) {
            const int cb = wv * 4 + j;
            ushort8 bf = *(const ushort8*)&W2f[(((cb * 16 + kb) * 64) + lane) * 8];
#pragma unroll
            for (int i = 0; i < RM; ++i) {
                acc[i][j] = __builtin_amdgcn_mfma_f32_16x16x32_bf16(
                    __builtin_bit_cast(bf16x8, af[i]),
                    __builtin_bit_cast(bf16x8, bf),
                    acc[i][j], 0, 0, 0);
            }
        }
    }

#pragma unroll
    for (int i = 0; i < RM; ++i)
#pragma unroll
        for (int j = 0; j < 4; ++j) {
            const int col = (wv * 4 + j) * 16 + l16;
#pragma unroll
            for (int rg_ = 0; rg_ < 4; ++rg_) {
                const int row = bid * TM + i * 16 + (lane >> 4) * 4 + rg_;
                out[(size_t)row * 256 + col] = fmaxf(acc[i][j][rg_], 0.f);
            }
        }
}

// ---------------------------------------------------------------------------
// Layer-2 GEMM (fallback path only)
// ---------------------------------------------------------------------------
__global__ __launch_bounds__(256)
void gemm2_kernel(const unsigned short* __restrict__ comb,
                  const unsigned short* __restrict__ Wfrag,
                  float* __restrict__ out)
{
    constexpr int TM = 32;
    __shared__ __align__(16) unsigned short B_lds[TM * KDIM];
    const int t   = threadIdx.x;
    const int bid = blockIdx.x;

    for (int i = t; i < TM * KDIM / 8; i += 256) {
        const int row = i >> 6;
        const int c8  = (i & 63) * 8;
        ushort8 v = *(const ushort8*)&comb[((size_t)(bid * TM + row)) * KDIM + c8];
        *(ushort8*)&B_lds[(row * KDIM + c8) ^ ((row & 7) << 3)] = v;
    }
    __syncthreads();

    constexpr int RM = TM / 16;
    const int wv = t >> 6, lane = t & 63, l16 = lane & 15, koff = (lane >> 4) * 8;
    f32x4 acc[RM][4];
#pragma unroll
    for (int i = 0; i < RM; ++i)
#pragma unroll
        for (int j = 0; j < 4; ++j) acc[i][j] = (f32x4){0.f, 0.f, 0.f, 0.f};

#pragma unroll 4
    for (int kb = 0; kb < 16; ++kb) {
        const int kbase = kb * 32 + koff;
        ushort8 af[RM];
#pragma unroll
        for (int i = 0; i < RM; ++i) {
            const int row = i * 16 + l16;
            af[i] = *(const ushort8*)&B_lds[(row * KDIM + kbase) ^ ((row & 7) << 3)];
        }
#pragma unroll
        for (int j = 0; j < 4; ++j) {
            const int cb = wv * 4 + j;
            ushort8 bf = *(const ushort8*)&Wfrag[(((cb * 16 + kb) * 64) + lane) * 8];
#pragma unroll
            for (int i = 0; i < RM; ++i) {
                acc[i][j] = __builtin_amdgcn_mfma_f32_16x16x32_bf16(
                    __builtin_bit_cast(bf16x8, af[i]),
                    __builtin_bit_cast(bf16x8, bf),
                    acc[i][j], 0, 0, 0);
            }
        }
    }

#pragma unroll
    for (int i = 0; i < RM; ++i)
#pragma unroll
        for (int j = 0; j < 4; ++j) {
            const int col = (wv * 4 + j) * 16 + l16;
#pragma unroll
            for (int rg_ = 0; rg_ < 4; ++rg_) {
                const int row = bid * TM + i * 16 + (lane >> 4) * 4 + rg_;
                out[(size_t)row * 256 + col] = fmaxf(acc[i][j][rg_], 0.f);
            }
        }
}

// ---------------------------------------------------------------------------
extern "C" void kernel_launch(void* const* d_in, const int* in_sizes, int n_in,
                              void* d_out, int out_size, void* d_ws, size_t ws_size,
                              hipStream_t stream)
{
    const int*   forest0 = (const int*)d_in[0];    // [8192]
    const int*   forest1 = (const int*)d_in[1];    // [8192*10]
    const int*   forest2 = (const int*)d_in[2];    // [81920*10]
    const float* FM      = (const float*)d_in[3];  // [100000*256]
    const float* W1      = (const float*)d_in[4];  // [512*256]
    const float* W2      = (const float*)d_in[5];  // [512*256]
    float*       out     = (float*)d_out;          // [8192*256]

    const size_t fmbElems  = (size_t)NNODES * F;                 // 25,600,000
    const size_t wElems    = (size_t)512 * 256;                  // per weight
    const size_t combElems = (size_t)NROOTS * KDIM;              // 4,194,304
    const size_t xnbElems  = (size_t)NROOTS * F;                 // 2,097,152
    const size_t baseBytes = (fmbElems + 2 * wElems + combElems) * sizeof(unsigned short);
    const size_t xnbBytes  = baseBytes + xnbElems * sizeof(unsigned short);

    if (ws_size >= baseBytes) {
        unsigned short* FMb  = (unsigned short*)d_ws;
        unsigned short* W1f  = FMb + fmbElems;
        unsigned short* W2f  = W1f + wElems;
        unsigned short* comb = W2f + wElems;
        unsigned short* xnb  = comb + combElems;

        // 1) fused weight + feature conversion (HBM-stream roofline)
        prep_kernel<<<dim3(128 + 2048), dim3(256), 0, stream>>>(
            FM, W1, W2, FMb, W1f, W2f);

        if (ws_size >= xnbBytes) {
            // 2) hop-1 + XNB side-product (per-root forest1 mean, bit-identical)
            hop_kernel<80, true, unsigned short, 512, true>
                <<<dim3(HOP1ROWS / 80), dim3(512), 0, stream>>>(
                FMb, forest1, forest2, W1f, comb, xnb);
            // 3) root: self gather + streamed xnb + layer-1 + layer-2
            root_kernel<true><<<dim3(NROOTS / 32), dim3(256), 0, stream>>>(
                FMb, forest0, forest1, W1f, W2f, comb, xnb, out);
        } else {
            // exact r4 path
            hop_kernel<80, true, unsigned short, 512, false>
                <<<dim3(HOP1ROWS / 80), dim3(512), 0, stream>>>(
                FMb, forest1, forest2, W1f, comb, nullptr);
            root_kernel<false><<<dim3(NROOTS / 32), dim3(256), 0, stream>>>(
                FMb, forest0, forest1, W1f, W2f, comb, nullptr, out);
        }
    } else {
        // fallback: original f32-gather path (~8.6 MB workspace)
        unsigned short* W1f  = (unsigned short*)d_ws;
        unsigned short* W2f  = W1f + wElems;
        unsigned short* comb = W2f + wElems;

        wconv_kernel<<<dim3(128), dim3(256), 0, stream>>>(W1, W2, W1f, W2f);
        hop_kernel<80, true, float, 256, false>
            <<<dim3(HOP1ROWS / 80), dim3(256), 0, stream>>>(
            FM, forest1, forest2, W1f, comb, nullptr);
        hop_kernel<32, false, float, 256, false>
            <<<dim3(NROOTS / 32), dim3(256), 0, stream>>>(
            FM, forest0, forest1, W1f, comb, nullptr);
        gemm2_kernel<<<dim3(NROOTS / 32), dim3(256), 0, stream>>>(comb, W2f, out);
    }
}